// Round 11
// baseline (51.022 us; speedup 1.0000x reference)
//
#include <hip/hip_runtime.h>
#include <math.h>

// x: [32,3,512,512] f32.
// Register-only row sweep, no LDS/barriers in stage 1.
// Each lane owns 8 cols (2 aligned float4 loads/row; wave spans 512 cols).
// Sobel separable via pair-sum pipeline: P[q] = x[q]+x[q+1] (ring of 2);
//   a = Po+Pn (vert [1,2,1]), b = Po-Pn (vert [1,0,-1]);
//   gx = a(c-1)-a(c+1), gy = b(c-1)+2b(c)+b(c+1); mag = v_sqrt_f32.
// Horizontal halo via 4 shuffles per mag row + 2 per pool row.
// 12 output rows/wave, 44 chunks/(b,c) (43 real + 1 dummy), 4224 waves.
// Distance-4 prefetch: 6-row prologue burst, then 1 load/magstep consumed
// 4 magsteps later -> L2/L3 latency hidden under VALU (r9 exposed it).
// Interior chunks (1..41) take a branch-free path (no row checks/masks);
// only chunks 0/42/43 run the guarded path. All ring indices compile-time.
// Grid: (11, 96) x 256.

template <bool SAFE>
__device__ __forceinline__ void sweep12(const float* __restrict__ xl,
                                        int row0, int lane,
                                        float& s_out, float& ss_out) {
  auto load8 = [&](int r, float* o) {
    if (SAFE && (unsigned)r >= 512u) {
#pragma unroll
      for (int k = 0; k < 8; ++k) o[k] = 0.f;
      return;
    }
    const float* p = xl + (size_t)r * 512;
    float4 u = *(const float4*)(p);
    float4 v = *(const float4*)(p + 4);
    o[0] = u.x; o[1] = u.y; o[2] = u.z; o[3] = u.w;
    o[4] = v.x; o[5] = v.y; o[6] = v.z; o[7] = v.w;
  };

  float xrow[16][8];   // slots: x row (row0-2+slot); dead slots pruned
  float P[2][8];       // pair-sum ring: pair q = x[q]+x[q+1] (slot units)
  float M[3][8];       // mag ring
  float s = 0.f, ss = 0.f;

  // prologue: burst-load rows row0-2 .. row0+3 (slots 0..5)
#pragma unroll
  for (int k = 0; k < 6; ++k) load8(row0 - 2 + k, xrow[k]);
#pragma unroll
  for (int j = 0; j < 8; ++j) P[0][j] = xrow[0][j] + xrow[1][j];

#pragma unroll
  for (int t = 0; t < 14; ++t) {
    // prefetch row row0+4+t into slot 6+t; consumed at magstep t+4
    if (t <= 9) load8(row0 + 4 + t, xrow[6 + t]);

    float* Po = P[t & 1];
    float* Pn = P[(t + 1) & 1];
#pragma unroll
    for (int j = 0; j < 8; ++j) Pn[j] = xrow[t + 1][j] + xrow[t + 2][j];

    const int rm = row0 - 1 + t;         // mag row for this step
    float* mg = M[t % 3];
    if (!SAFE || (unsigned)rm < 512u) {  // wave-uniform (constant-folded FAST)
      float a[8], b[8];
#pragma unroll
      for (int j = 0; j < 8; ++j) { a[j] = Po[j] + Pn[j]; b[j] = Po[j] - Pn[j]; }
      float aL = __shfl_up(a[7], 1), aR = __shfl_down(a[0], 1);
      float bL = __shfl_up(b[7], 1), bR = __shfl_down(b[0], 1);
      if (lane == 0)  { aL = 0.f; bL = 0.f; }   // image col -1 = 0
      if (lane == 63) { aR = 0.f; bR = 0.f; }   // image col 512 = 0
#pragma unroll
      for (int j = 0; j < 8; ++j) {
        float am = j ? a[j - 1] : aL;
        float ap = (j < 7) ? a[j + 1] : aR;
        float bm = j ? b[j - 1] : bL;
        float bp = (j < 7) ? b[j + 1] : bR;
        float gx = am - ap;                      // horiz [1,0,-1]
        float gy = fmaf(2.f, b[j], bm + bp);     // horiz [1,2,1]
        float m2 = fmaf(gx, gx, 1e-6f);
        m2 = fmaf(gy, gy, m2);
        mg[j] = __builtin_amdgcn_sqrtf(m2);
      }
    } else {
#pragma unroll
      for (int j = 0; j < 8; ++j) mg[j] = 0.f;
    }

    // pool output row (row0+t-2) once 3 mag rows exist
    if (t >= 2) {
      if (!SAFE || (unsigned)(row0 + t - 2) < 512u) {
        float* m0 = M[(t - 2) % 3];
        float* m1 = M[(t - 1) % 3];
        float cs[8];
#pragma unroll
        for (int j = 0; j < 8; ++j) cs[j] = (m0[j] + mg[j]) + m1[j];
        float csL = __shfl_up(cs[7], 1), csR = __shfl_down(cs[0], 1);
        if (lane == 0) csL = 0.f;
        if (lane == 63) csR = 0.f;
#pragma unroll
        for (int j = 0; j < 8; ++j) {
          float cm = j ? cs[j - 1] : csL;
          float cp = (j < 7) ? cs[j + 1] : csR;
          float tt = (cm + cp) + cs[j];
          s += tt;
          ss = fmaf(tt, tt, ss);
        }
      }
    }
  }
  s_out = s;
  ss_out = ss;
}

__global__ __launch_bounds__(256) void sobel_pool_stats(
    const float* __restrict__ x, double* __restrict__ parts) {
  const int tid = threadIdx.x;
  const int lane = tid & 63;
  const int w = tid >> 6;
  const int bc = blockIdx.y;                 // 0..95
  const int chunk = blockIdx.x * 4 + w;      // 0..43 (43 = dummy)
  const int row0 = chunk * 12;
  const float* __restrict__ xl = x + (size_t)bc * (512 * 512) + lane * 8;

  float s, ss;
  if (chunk >= 1 && chunk <= 41) sweep12<false>(xl, row0, lane, s, ss);
  else                           sweep12<true>(xl, row0, lane, s, ss);

  // per-wave double reduction; fold deferred /9, /81
  double ds = (double)s * (1.0 / 9.0);
  double dss = (double)ss * (1.0 / 81.0);
  for (int off = 32; off > 0; off >>= 1) {
    ds += __shfl_down(ds, off);
    dss += __shfl_down(dss, off);
  }
  if (lane == 0) {
    size_t idx = ((size_t)bc * 44 + chunk) * 2;
    parts[idx] = ds;
    parts[idx + 1] = dss;
  }
}

// Reduce 44 wave-partials per (b,c), feats [32,6]=[m0,s0,m1,s1,m2,s2], MLP.
__global__ __launch_bounds__(256) void stats_mlp(
    const double* __restrict__ parts,
    const float* __restrict__ w1, const float* __restrict__ b1,
    const float* __restrict__ w2, const float* __restrict__ b2,
    float* __restrict__ out) {
  __shared__ float feats[32 * 6];
  __shared__ float hbuf[32 * 32];
  const int tid = threadIdx.x;

  if (tid < 96) {
    int b = tid / 3;
    int ch = tid - b * 3;
    double s = 0.0, ss = 0.0;
    const double2* p = (const double2*)(parts + (size_t)tid * 88);
#pragma unroll
    for (int t = 0; t < 44; ++t) {
      double2 v = p[t];
      s += v.x;
      ss += v.y;
    }
    const double N = 262144.0;
    double mean = s / N;
    double var = (ss - s * s / N) / (N - 1.0);
    if (var < 0.0) var = 0.0;
    feats[b * 6 + 2 * ch] = (float)mean;
    feats[b * 6 + 2 * ch + 1] = (float)sqrt(var);
  }
  __syncthreads();

  for (int idx = tid; idx < 32 * 32; idx += 256) {
    int i = idx >> 5, j = idx & 31;
    float acc = b1[j];
#pragma unroll
    for (int k = 0; k < 6; ++k) acc += feats[i * 6 + k] * w1[j * 6 + k];
    hbuf[idx] = acc > 0.f ? acc : 0.f;
  }
  __syncthreads();

  for (int idx = tid; idx < 2048; idx += 256) {
    int i = idx >> 6, o = idx & 63;
    float acc = b2[o];
#pragma unroll
    for (int j = 0; j < 32; ++j) acc += hbuf[i * 32 + j] * w2[o * 32 + j];
    out[idx] = acc;
  }
}

extern "C" void kernel_launch(void* const* d_in, const int* in_sizes, int n_in,
                              void* d_out, int out_size, void* d_ws, size_t ws_size,
                              hipStream_t stream) {
  const float* x = (const float*)d_in[0];
  const float* w1 = (const float*)d_in[1];
  const float* b1 = (const float*)d_in[2];
  const float* w2 = (const float*)d_in[3];
  const float* b2 = (const float*)d_in[4];
  float* out = (float*)d_out;
  double* parts = (double*)d_ws;  // 96*44*2 doubles = 67584 B

  dim3 grid(11, 96);
  sobel_pool_stats<<<grid, 256, 0, stream>>>(x, parts);
  stats_mlp<<<1, 256, 0, stream>>>(parts, w1, b1, w2, b2, out);
}

// Round 12
// 38.043 us; speedup vs baseline: 1.3412x; 1.3412x over previous
//
#include <hip/hip_runtime.h>
#include <math.h>

// x: [32,3,512,512] f32.
// Register-only row sweep, no LDS/barriers in stage 1.
// Each lane owns 8 cols (2 aligned float4 loads/row; wave spans 512 cols).
// Sobel separable via pair-sum ring: Pn = x[r-1]+x[r] (ring of 2);
//   a = Po+Pn (vert [1,2,1]), b = Po-Pn (vert [1,0,-1]);
//   gx = a(c-1)-a(c+1), gy = b(c-1)+2b(c)+b(c+1); mag = v_sqrt_f32.
// Horizontal halo via 4 shuffles per mag row + 2 per pool row.
// 12 output rows/wave, 44 chunks/(b,c) (43 real + 1 dummy), 4224 waves.
// DISTANCE-2 prefetch on a 4-buffer x-row ring (32 VGPR): load at step t
// is consumed at t+2 (~500cy x 4-wave TLP of cover). r11's distance-4 kept
// 6 buffers -> VGPR 132 > 128 boundary -> occupancy 8%. Budget: xb4(32)+
// P(16)+M(24)+ab(16) ~ 105 VGPR, 4 waves/SIMD.
// Interior chunks (1..41): branch-free FAST path; 0/42/43: guarded SAFE.
// Grid: (11, 96) x 256.

template <bool SAFE>
__device__ __forceinline__ void sweep12(const float* __restrict__ xl,
                                        int row0, int lane,
                                        float& s_out, float& ss_out) {
  auto load8 = [&](int r, float* o) {
    if (SAFE && (unsigned)r >= 512u) {
#pragma unroll
      for (int k = 0; k < 8; ++k) o[k] = 0.f;
      return;
    }
    const float* p = xl + (size_t)r * 512;
    float4 u = *(const float4*)(p);
    float4 v = *(const float4*)(p + 4);
    o[0] = u.x; o[1] = u.y; o[2] = u.z; o[3] = u.w;
    o[4] = v.x; o[5] = v.y; o[6] = v.z; o[7] = v.w;
  };

  float xb4[4][8];     // x-row ring: slot (r - row0) & 3
  float P[2][8];       // pair-sum ring
  float M[3][8];       // mag ring
  float s = 0.f, ss = 0.f;

  // prologue: rows row0-2 (temp), row0-1, row0, row0+1
  {
    float t0[8];
    load8(row0 - 2, t0);
    load8(row0 - 1, xb4[3]);
#pragma unroll
    for (int j = 0; j < 8; ++j) P[1][j] = t0[j] + xb4[3][j];  // Po for t=0
  }
  load8(row0, xb4[0]);
  load8(row0 + 1, xb4[1]);

#pragma unroll
  for (int t = 0; t < 14; ++t) {
    // distance-2 prefetch: row row0+2+t -> slot (t+2)&3, consumed at t+2/t+3
    if (t <= 11) load8(row0 + 2 + t, xb4[(t + 2) & 3]);

    float* Po = P[(t + 1) & 1];
    float* Pn = P[t & 1];
    float* xprev = xb4[(t + 3) & 3];   // row row0+t-1
    float* xcur = xb4[t & 3];          // row row0+t
#pragma unroll
    for (int j = 0; j < 8; ++j) Pn[j] = xprev[j] + xcur[j];

    const int rm = row0 - 1 + t;       // mag row this step emits
    float* mg = M[t % 3];
    if (!SAFE || (unsigned)rm < 512u) {  // wave-uniform; constant-folded FAST
      float a[8], b[8];
#pragma unroll
      for (int j = 0; j < 8; ++j) { a[j] = Po[j] + Pn[j]; b[j] = Po[j] - Pn[j]; }
      float aL = __shfl_up(a[7], 1), aR = __shfl_down(a[0], 1);
      float bL = __shfl_up(b[7], 1), bR = __shfl_down(b[0], 1);
      if (lane == 0)  { aL = 0.f; bL = 0.f; }   // image col -1 = 0
      if (lane == 63) { aR = 0.f; bR = 0.f; }   // image col 512 = 0
#pragma unroll
      for (int j = 0; j < 8; ++j) {
        float am = j ? a[j - 1] : aL;
        float ap = (j < 7) ? a[j + 1] : aR;
        float bm = j ? b[j - 1] : bL;
        float bp = (j < 7) ? b[j + 1] : bR;
        float gx = am - ap;                      // horiz [1,0,-1]
        float gy = fmaf(2.f, b[j], bm + bp);     // horiz [1,2,1]
        float m2 = fmaf(gx, gx, 1e-6f);
        m2 = fmaf(gy, gy, m2);
        mg[j] = __builtin_amdgcn_sqrtf(m2);
      }
    } else {
#pragma unroll
      for (int j = 0; j < 8; ++j) mg[j] = 0.f;
    }

    // pool output row row0+t-2 once 3 mag rows exist
    if (t >= 2) {
      if (!SAFE || (unsigned)(row0 + t - 2) < 512u) {
        float* m0 = M[(t - 2) % 3];
        float* m1 = M[(t - 1) % 3];
        float cs[8];
#pragma unroll
        for (int j = 0; j < 8; ++j) cs[j] = (m0[j] + mg[j]) + m1[j];
        float csL = __shfl_up(cs[7], 1), csR = __shfl_down(cs[0], 1);
        if (lane == 0) csL = 0.f;
        if (lane == 63) csR = 0.f;
#pragma unroll
        for (int j = 0; j < 8; ++j) {
          float cm = j ? cs[j - 1] : csL;
          float cp = (j < 7) ? cs[j + 1] : csR;
          float tt = (cm + cp) + cs[j];
          s += tt;
          ss = fmaf(tt, tt, ss);
        }
      }
    }
  }
  s_out = s;
  ss_out = ss;
}

__global__ __launch_bounds__(256) void sobel_pool_stats(
    const float* __restrict__ x, double* __restrict__ parts) {
  const int tid = threadIdx.x;
  const int lane = tid & 63;
  const int w = tid >> 6;
  const int bc = blockIdx.y;                 // 0..95
  const int chunk = blockIdx.x * 4 + w;      // 0..43 (43 = dummy)
  const int row0 = chunk * 12;
  const float* __restrict__ xl = x + (size_t)bc * (512 * 512) + lane * 8;

  float s, ss;
  if (chunk >= 1 && chunk <= 41) sweep12<false>(xl, row0, lane, s, ss);
  else                           sweep12<true>(xl, row0, lane, s, ss);

  // per-wave double reduction; fold deferred /9, /81
  double ds = (double)s * (1.0 / 9.0);
  double dss = (double)ss * (1.0 / 81.0);
  for (int off = 32; off > 0; off >>= 1) {
    ds += __shfl_down(ds, off);
    dss += __shfl_down(dss, off);
  }
  if (lane == 0) {
    size_t idx = ((size_t)bc * 44 + chunk) * 2;
    parts[idx] = ds;
    parts[idx + 1] = dss;
  }
}

// Reduce 44 wave-partials per (b,c), feats [32,6]=[m0,s0,m1,s1,m2,s2], MLP.
__global__ __launch_bounds__(256) void stats_mlp(
    const double* __restrict__ parts,
    const float* __restrict__ w1, const float* __restrict__ b1,
    const float* __restrict__ w2, const float* __restrict__ b2,
    float* __restrict__ out) {
  __shared__ float feats[32 * 6];
  __shared__ float hbuf[32 * 32];
  const int tid = threadIdx.x;

  if (tid < 96) {
    int b = tid / 3;
    int ch = tid - b * 3;
    double s = 0.0, ss = 0.0;
    const double2* p = (const double2*)(parts + (size_t)tid * 88);
#pragma unroll
    for (int t = 0; t < 44; ++t) {
      double2 v = p[t];
      s += v.x;
      ss += v.y;
    }
    const double N = 262144.0;
    double mean = s / N;
    double var = (ss - s * s / N) / (N - 1.0);
    if (var < 0.0) var = 0.0;
    feats[b * 6 + 2 * ch] = (float)mean;
    feats[b * 6 + 2 * ch + 1] = (float)sqrt(var);
  }
  __syncthreads();

  for (int idx = tid; idx < 32 * 32; idx += 256) {
    int i = idx >> 5, j = idx & 31;
    float acc = b1[j];
#pragma unroll
    for (int k = 0; k < 6; ++k) acc += feats[i * 6 + k] * w1[j * 6 + k];
    hbuf[idx] = acc > 0.f ? acc : 0.f;
  }
  __syncthreads();

  for (int idx = tid; idx < 2048; idx += 256) {
    int i = idx >> 6, o = idx & 63;
    float acc = b2[o];
#pragma unroll
    for (int j = 0; j < 32; ++j) acc += hbuf[i * 32 + j] * w2[o * 32 + j];
    out[idx] = acc;
  }
}

extern "C" void kernel_launch(void* const* d_in, const int* in_sizes, int n_in,
                              void* d_out, int out_size, void* d_ws, size_t ws_size,
                              hipStream_t stream) {
  const float* x = (const float*)d_in[0];
  const float* w1 = (const float*)d_in[1];
  const float* b1 = (const float*)d_in[2];
  const float* w2 = (const float*)d_in[3];
  const float* b2 = (const float*)d_in[4];
  float* out = (float*)d_out;
  double* parts = (double*)d_ws;  // 96*44*2 doubles = 67584 B

  dim3 grid(11, 96);
  sobel_pool_stats<<<grid, 256, 0, stream>>>(x, parts);
  stats_mlp<<<1, 256, 0, stream>>>(parts, w1, b1, w2, b2, out);
}